// Round 1
// baseline (3243.127 us; speedup 1.0000x reference)
//
#include <hip/hip_runtime.h>

#define NEG_INF_F (-1.0e9f)

// C[m,n] = sum_k A[m,k] * B(n,k)   (BT=true:  B is [N,K], NT gemm)
//                                   (BT=false: B is [K,N], NN gemm)
// Optional epilogue: C[m,n] += NEG_INF * mask[n]  (per-batch mask)
template <bool BT>
__global__ __launch_bounds__(256) void gemm_kernel(
    const float* __restrict__ A, long long strideA, int lda,
    const float* __restrict__ B, long long strideB, int ldb,
    float* __restrict__ C, long long strideC, int ldc,
    int M, int N, int K,
    const int* __restrict__ mask, long long strideMask)
{
    const int b = blockIdx.z;
    A += (long long)b * strideA;
    B += (long long)b * strideB;
    C += (long long)b * strideC;

    __shared__ float As[16][64];
    __shared__ float Bs[16][64];

    const int tid = threadIdx.x;   // 0..255
    const int tx  = tid & 15;
    const int ty  = tid >> 4;

    const int rowBase = blockIdx.x * 64;
    const int colBase = blockIdx.y * 64;

    float acc[4][4] = {};

    // A-tile: 64 rows x 16 k; one float4 per thread
    const int arow = tid >> 2;          // 0..63
    const int acol = (tid & 3) * 4;     // 0,4,8,12

    for (int k0 = 0; k0 < K; k0 += 16) {
        {
            const float4 va = *reinterpret_cast<const float4*>(
                &A[(long long)(rowBase + arow) * lda + k0 + acol]);
            As[acol + 0][arow] = va.x;
            As[acol + 1][arow] = va.y;
            As[acol + 2][arow] = va.z;
            As[acol + 3][arow] = va.w;
        }
        if (BT) {
            const float4 vb = *reinterpret_cast<const float4*>(
                &B[(long long)(colBase + arow) * ldb + k0 + acol]);
            Bs[acol + 0][arow] = vb.x;
            Bs[acol + 1][arow] = vb.y;
            Bs[acol + 2][arow] = vb.z;
            Bs[acol + 3][arow] = vb.w;
        } else {
            const int brow = tid >> 4;        // 0..15 (k)
            const int bcol = (tid & 15) * 4;  // 0..60 (n)
            const float4 vb = *reinterpret_cast<const float4*>(
                &B[(long long)(k0 + brow) * ldb + colBase + bcol]);
            *reinterpret_cast<float4*>(&Bs[brow][bcol]) = vb;
        }
        __syncthreads();

#pragma unroll
        for (int k = 0; k < 16; ++k) {
            float a[4], bb[4];
            *reinterpret_cast<float4*>(a)  = *reinterpret_cast<const float4*>(&As[k][ty * 4]);
            *reinterpret_cast<float4*>(bb) = *reinterpret_cast<const float4*>(&Bs[k][tx * 4]);
#pragma unroll
            for (int i = 0; i < 4; ++i)
#pragma unroll
                for (int j = 0; j < 4; ++j)
                    acc[i][j] += a[i] * bb[j];
        }
        __syncthreads();
    }

    float maskv[4] = {0.f, 0.f, 0.f, 0.f};
    if (mask) {
        const int* mb = mask + (long long)b * strideMask;
#pragma unroll
        for (int j = 0; j < 4; ++j)
            maskv[j] = NEG_INF_F * (float)mb[colBase + tx * 4 + j];
    }

#pragma unroll
    for (int i = 0; i < 4; ++i) {
        float4 v;
        v.x = acc[i][0] + maskv[0];
        v.y = acc[i][1] + maskv[1];
        v.z = acc[i][2] + maskv[2];
        v.w = acc[i][3] + maskv[3];
        *reinterpret_cast<float4*>(
            &C[(long long)(rowBase + ty * 4 + i) * ldc + colBase + tx * 4]) = v;
    }
}

// In-place row softmax: rows = B*S = 16384, cols = 2048.
__global__ __launch_bounds__(256) void softmax_kernel(float* __restrict__ s)
{
    const long long row = blockIdx.x;
    float* p = s + row * 2048;
    const int tid = threadIdx.x;

    float v[8];
    *reinterpret_cast<float4*>(&v[0]) = *reinterpret_cast<const float4*>(&p[tid * 8]);
    *reinterpret_cast<float4*>(&v[4]) = *reinterpret_cast<const float4*>(&p[tid * 8 + 4]);

    float m = v[0];
#pragma unroll
    for (int i = 1; i < 8; ++i) m = fmaxf(m, v[i]);
#pragma unroll
    for (int off = 1; off < 64; off <<= 1) m = fmaxf(m, __shfl_xor(m, off));

    __shared__ float redm[4];
    __shared__ float reds[4];
    if ((tid & 63) == 0) redm[tid >> 6] = m;
    __syncthreads();
    m = fmaxf(fmaxf(redm[0], redm[1]), fmaxf(redm[2], redm[3]));

    float sum = 0.f;
#pragma unroll
    for (int i = 0; i < 8; ++i) {
        v[i] = __expf(v[i] - m);
        sum += v[i];
    }
#pragma unroll
    for (int off = 1; off < 64; off <<= 1) sum += __shfl_xor(sum, off);
    if ((tid & 63) == 0) reds[tid >> 6] = sum;
    __syncthreads();
    sum = reds[0] + reds[1] + reds[2] + reds[3];

    const float inv = 1.0f / sum;
#pragma unroll
    for (int i = 0; i < 8; ++i) v[i] *= inv;

    *reinterpret_cast<float4*>(&p[tid * 8])     = *reinterpret_cast<const float4*>(&v[0]);
    *reinterpret_cast<float4*>(&p[tid * 8 + 4]) = *reinterpret_cast<const float4*>(&v[4]);
}

extern "C" void kernel_launch(void* const* d_in, const int* in_sizes, int n_in,
                              void* d_out, int out_size, void* d_ws, size_t ws_size,
                              hipStream_t stream)
{
    (void)in_sizes; (void)n_in; (void)out_size; (void)ws_size;

    const int B = 8, S = 2048, D = 1024;
    const long long BS = (long long)B * S;          // 16384
    const long long SD = (long long)S * D;          // 2048*1024
    const long long SS = (long long)S * S;          // 2048*2048

    const float* x    = (const float*)d_in[0];
    const int*   mask = (const int*)d_in[1];
    const float* wq   = (const float*)d_in[2];
    const float* wk   = (const float*)d_in[3];
    const float* wv   = (const float*)d_in[4];

    float* out = (float*)d_out;                     // [B,S,D]
    float* s   = out + BS * D;                      // [B,S,S]

    float* Q = (float*)d_ws;                        // [BS, D]
    float* K = Q + BS * D;                          // [BS, D]
    // V reuses Q's buffer after scores are done (stream-ordered).

    dim3 blk(256);

    // Projections: M=16384, N=1024, K=1024, batch=1
    dim3 gProj(16384 / 64, 1024 / 64, 1);
    gemm_kernel<true><<<gProj, blk, 0, stream>>>(
        x, 0, D, wq, 0, D, Q, 0, D, (int)BS, D, D, nullptr, 0);
    gemm_kernel<true><<<gProj, blk, 0, stream>>>(
        x, 0, D, wk, 0, D, K, 0, D, (int)BS, D, D, nullptr, 0);

    // Scores: per batch M=N=2048, K=1024, fused mask add
    dim3 gScore(2048 / 64, 2048 / 64, 8);
    gemm_kernel<true><<<gScore, blk, 0, stream>>>(
        Q, SD, D, K, SD, D, s, SS, S, S, S, D, mask, S);

    // Softmax in place on s
    softmax_kernel<<<dim3(16384), blk, 0, stream>>>(s);

    // V projection (overwrites Q buffer — Q no longer needed)
    float* V = Q;
    gemm_kernel<true><<<gProj, blk, 0, stream>>>(
        x, 0, D, wv, 0, D, V, 0, D, (int)BS, D, D, nullptr, 0);

    // PV: per batch, NN gemm: out[b] = s[b] (2048x2048) @ V[b] (2048x1024)
    dim3 gPV(2048 / 64, 1024 / 64, 8);
    gemm_kernel<false><<<gPV, blk, 0, stream>>>(
        s, SS, S, V, SD, D, out, SD, D, S, D, S, nullptr, 0);
}

// Round 2
// 901.230 us; speedup vs baseline: 3.5986x; 3.5986x over previous
//
#include <hip/hip_runtime.h>

#define NEG_INF_F (-1.0e9f)

typedef short bf16x8 __attribute__((ext_vector_type(8)));
typedef float f32x4 __attribute__((ext_vector_type(4)));

__device__ inline unsigned short bf_rne(float f) {
    unsigned u = __builtin_bit_cast(unsigned, f);
    u = (u + 0x7fffu + ((u >> 16) & 1u)) >> 16;
    return (unsigned short)u;
}
__device__ inline float bf_to_f32(unsigned short h) {
    unsigned u = ((unsigned)h) << 16;
    return __builtin_bit_cast(float, u);
}

// f32 -> (hi, lo) bf16 split, vectorized
__global__ __launch_bounds__(256) void split2_kernel(
    const float* __restrict__ in, unsigned short* __restrict__ hi,
    unsigned short* __restrict__ lo, long long n)
{
    for (long long i = ((long long)blockIdx.x * 256 + threadIdx.x) * 4; i < n;
         i += (long long)gridDim.x * 256 * 4) {
        float4 v = *reinterpret_cast<const float4*>(&in[i]);
        ushort4 h, l;
        h.x = bf_rne(v.x); l.x = bf_rne(v.x - bf_to_f32(h.x));
        h.y = bf_rne(v.y); l.y = bf_rne(v.y - bf_to_f32(h.y));
        h.z = bf_rne(v.z); l.z = bf_rne(v.z - bf_to_f32(h.z));
        h.w = bf_rne(v.w); l.w = bf_rne(v.w - bf_to_f32(h.w));
        *reinterpret_cast<ushort4*>(&hi[i]) = h;
        *reinterpret_cast<ushort4*>(&lo[i]) = l;
    }
}

// C = A * B(^T) with bf16 MFMA, 128x128 tile, BK=32, 4 waves (2x2), 4x4 frags/wave.
// TERMS: 3 = hi/lo split (Ah*Bh + Al*Bh + Ah*Bl), 1 = hi only.
// BT: true -> B is [N,K]; false -> B is [K,N] (requires TERMS==1, !BCVT).
// OMODE: 0 = f32 C (+ optional NEG_INF*mask[col]); 1 = split bf16 (Ch,Cl); 2 = bf16 (Ch).
// BCVT: B operand is f32, converted to bf16-hi during staging (requires TERMS==1, BT).
template <int TERMS, bool BT, int OMODE, bool BCVT>
__global__ __launch_bounds__(256) void mfma_gemm(
    const unsigned short* __restrict__ Ah_g, const unsigned short* __restrict__ Al_g,
    long long strideA, int lda,
    const void* __restrict__ Bh_gv, const unsigned short* __restrict__ Bl_g,
    long long strideB, int ldb,
    float* __restrict__ Cf, unsigned short* __restrict__ Ch, unsigned short* __restrict__ Cl,
    long long strideC, int ldc, int K,
    const int* __restrict__ mask, long long strideMask)
{
    const int b = blockIdx.z;
    const int tid = threadIdx.x;
    const int rowBase = blockIdx.x * 128;
    const int colBase = blockIdx.y * 128;

    Ah_g += (long long)b * strideA;
    if constexpr (TERMS == 3) { Al_g += (long long)b * strideA; }

    const unsigned short* Bh_gs = nullptr;
    const float* Bh_gf = nullptr;
    if constexpr (BCVT) Bh_gf = (const float*)Bh_gv + (long long)b * strideB;
    else                Bh_gs = (const unsigned short*)Bh_gv + (long long)b * strideB;
    if constexpr (TERMS == 3) { Bl_g += (long long)b * strideB; }

    __shared__ unsigned short AsH[128][40];
    __shared__ unsigned short BsH[128][40];
    __shared__ unsigned short AsL[(TERMS == 3) ? 128 : 1][40];
    __shared__ unsigned short BsL[(TERMS == 3) ? 128 : 1][40];

    const int w = tid >> 6;
    const int lane = tid & 63;
    const int wr = w >> 1, wc = w & 1;
    const int lr = lane & 15, lg = lane >> 4;

    f32x4 acc[4][4] = {};

    for (int k0 = 0; k0 < K; k0 += 32) {
        __syncthreads();
        // ---- stage A tile (bf16 [M,K]) : 128 rows x 32 k ----
#pragma unroll
        for (int part = 0; part < 2; ++part) {
            const int e = (part * 256 + tid) * 8;
            const int r = e >> 5;
            const int kk = e & 31;
            uint4 v = *reinterpret_cast<const uint4*>(
                &Ah_g[(long long)(rowBase + r) * lda + k0 + kk]);
            *reinterpret_cast<uint4*>(&AsH[r][kk]) = v;
            if constexpr (TERMS == 3) {
                uint4 v2 = *reinterpret_cast<const uint4*>(
                    &Al_g[(long long)(rowBase + r) * lda + k0 + kk]);
                *reinterpret_cast<uint4*>(&AsL[r][kk]) = v2;
            }
        }
        // ---- stage B tile ----
        if constexpr (BT) {
            if constexpr (BCVT) {
#pragma unroll
                for (int part = 0; part < 4; ++part) {
                    const int e = (part * 256 + tid) * 4;
                    const int r = e >> 5;
                    const int kk = e & 31;
                    float4 v = *reinterpret_cast<const float4*>(
                        &Bh_gf[(long long)(colBase + r) * ldb + k0 + kk]);
                    ushort4 hcv;
                    hcv.x = bf_rne(v.x); hcv.y = bf_rne(v.y);
                    hcv.z = bf_rne(v.z); hcv.w = bf_rne(v.w);
                    *reinterpret_cast<ushort4*>(&BsH[r][kk]) = hcv;
                }
            } else {
#pragma unroll
                for (int part = 0; part < 2; ++part) {
                    const int e = (part * 256 + tid) * 8;
                    const int r = e >> 5;
                    const int kk = e & 31;
                    uint4 v = *reinterpret_cast<const uint4*>(
                        &Bh_gs[(long long)(colBase + r) * ldb + k0 + kk]);
                    *reinterpret_cast<uint4*>(&BsH[r][kk]) = v;
                    if constexpr (TERMS == 3) {
                        uint4 v2 = *reinterpret_cast<const uint4*>(
                            &Bl_g[(long long)(colBase + r) * ldb + k0 + kk]);
                        *reinterpret_cast<uint4*>(&BsL[r][kk]) = v2;
                    }
                }
            }
        } else {
            // B is [K,N] bf16 (PV). Stage transposed into [n][k] LDS layout.
#pragma unroll
            for (int part = 0; part < 2; ++part) {
                const int e = (part * 256 + tid) * 8;
                const int kk = e >> 7;
                const int n = e & 127;
                uint4 v = *reinterpret_cast<const uint4*>(
                    &Bh_gs[(long long)(k0 + kk) * ldb + colBase + n]);
                unsigned short vs[8];
                *reinterpret_cast<uint4*>(vs) = v;
#pragma unroll
                for (int q = 0; q < 8; ++q) BsH[n + q][kk] = vs[q];
            }
        }
        __syncthreads();

        // ---- fragments + MFMA ----
        bf16x8 ah[4], bh[4], al[4], bl[4];
#pragma unroll
        for (int i = 0; i < 4; ++i) {
            ah[i] = *reinterpret_cast<const bf16x8*>(&AsH[wr * 64 + i * 16 + lr][lg * 8]);
            bh[i] = *reinterpret_cast<const bf16x8*>(&BsH[wc * 64 + i * 16 + lr][lg * 8]);
            if constexpr (TERMS == 3) {
                al[i] = *reinterpret_cast<const bf16x8*>(&AsL[wr * 64 + i * 16 + lr][lg * 8]);
                bl[i] = *reinterpret_cast<const bf16x8*>(&BsL[wc * 64 + i * 16 + lr][lg * 8]);
            }
        }
#pragma unroll
        for (int i = 0; i < 4; ++i)
#pragma unroll
            for (int j = 0; j < 4; ++j) {
                acc[i][j] = __builtin_amdgcn_mfma_f32_16x16x32_bf16(ah[i], bh[j], acc[i][j], 0, 0, 0);
                if constexpr (TERMS == 3) {
                    acc[i][j] = __builtin_amdgcn_mfma_f32_16x16x32_bf16(al[i], bh[j], acc[i][j], 0, 0, 0);
                    acc[i][j] = __builtin_amdgcn_mfma_f32_16x16x32_bf16(ah[i], bl[j], acc[i][j], 0, 0, 0);
                }
            }
    }

    // ---- epilogue ----
#pragma unroll
    for (int j = 0; j < 4; ++j) {
        const int col = colBase + wc * 64 + j * 16 + lr;
        float mv = 0.f;
        if (OMODE == 0 && mask != nullptr)
            mv = NEG_INF_F * (float)mask[(long long)b * strideMask + col];
#pragma unroll
        for (int i = 0; i < 4; ++i) {
#pragma unroll
            for (int r2 = 0; r2 < 4; ++r2) {
                const int row = rowBase + wr * 64 + i * 16 + lg * 4 + r2;
                const long long idx = (long long)b * strideC + (long long)row * ldc + col;
                const float v = acc[i][j][r2] + mv;
                if constexpr (OMODE == 0) {
                    Cf[idx] = v;
                } else if constexpr (OMODE == 1) {
                    const unsigned short h = bf_rne(v);
                    Ch[idx] = h;
                    Cl[idx] = bf_rne(v - bf_to_f32(h));
                } else {
                    Ch[idx] = bf_rne(v);
                }
            }
        }
    }
}

// In-place f32 row softmax (rows=16384, cols=2048) + bf16 copy for PV.
__global__ __launch_bounds__(256) void softmax_kernel(
    float* __restrict__ s, unsigned short* __restrict__ p)
{
    const long long row = blockIdx.x;
    float* sp = s + row * 2048;
    const int tid = threadIdx.x;

    float v[8];
    *reinterpret_cast<float4*>(&v[0]) = *reinterpret_cast<const float4*>(&sp[tid * 8]);
    *reinterpret_cast<float4*>(&v[4]) = *reinterpret_cast<const float4*>(&sp[tid * 8 + 4]);

    float m = v[0];
#pragma unroll
    for (int i = 1; i < 8; ++i) m = fmaxf(m, v[i]);
#pragma unroll
    for (int off = 1; off < 64; off <<= 1) m = fmaxf(m, __shfl_xor(m, off));

    __shared__ float redm[4];
    __shared__ float reds[4];
    if ((tid & 63) == 0) redm[tid >> 6] = m;
    __syncthreads();
    m = fmaxf(fmaxf(redm[0], redm[1]), fmaxf(redm[2], redm[3]));

    float sum = 0.f;
#pragma unroll
    for (int i = 0; i < 8; ++i) {
        v[i] = __expf(v[i] - m);
        sum += v[i];
    }
#pragma unroll
    for (int off = 1; off < 64; off <<= 1) sum += __shfl_xor(sum, off);
    if ((tid & 63) == 0) reds[tid >> 6] = sum;
    __syncthreads();
    sum = reds[0] + reds[1] + reds[2] + reds[3];

    const float inv = 1.0f / sum;
#pragma unroll
    for (int i = 0; i < 8; ++i) v[i] *= inv;

    *reinterpret_cast<float4*>(&sp[tid * 8])     = *reinterpret_cast<const float4*>(&v[0]);
    *reinterpret_cast<float4*>(&sp[tid * 8 + 4]) = *reinterpret_cast<const float4*>(&v[4]);

    ushort4 o0, o1;
    o0.x = bf_rne(v[0]); o0.y = bf_rne(v[1]); o0.z = bf_rne(v[2]); o0.w = bf_rne(v[3]);
    o1.x = bf_rne(v[4]); o1.y = bf_rne(v[5]); o1.z = bf_rne(v[6]); o1.w = bf_rne(v[7]);
    *reinterpret_cast<ushort4*>(&p[row * 2048 + tid * 8])     = o0;
    *reinterpret_cast<ushort4*>(&p[row * 2048 + tid * 8 + 4]) = o1;
}

extern "C" void kernel_launch(void* const* d_in, const int* in_sizes, int n_in,
                              void* d_out, int out_size, void* d_ws, size_t ws_size,
                              hipStream_t stream)
{
    (void)in_sizes; (void)n_in; (void)out_size; (void)ws_size;

    const int S = 2048, D = 1024;
    const long long BS  = 8LL * S;        // 16384
    const long long SD  = (long long)S * D;
    const long long SS  = (long long)S * S;
    const long long BSD = BS * D;         // 16.78M elems
    const long long DD  = (long long)D * D;

    const float* x    = (const float*)d_in[0];
    const int*   mask = (const int*)d_in[1];
    const float* wq   = (const float*)d_in[2];
    const float* wk   = (const float*)d_in[3];
    const float* wv   = (const float*)d_in[4];

    float* out = (float*)d_out;           // [BS, D] f32 (final)
    float* s   = out + BSD;               // [B, S, S] f32 (final)

    // ws: Qh | Ql | Kh | Kl  (bf16, each BSD elems) = 134 MB total
    unsigned short* Qh = (unsigned short*)d_ws;
    unsigned short* Ql = Qh + BSD;
    unsigned short* Kh = Ql + BSD;
    unsigned short* Kl = Kh + BSD;

    // x split lives in d_out's out-region until PV overwrites it
    unsigned short* xh = (unsigned short*)out;
    unsigned short* xl = xh + BSD;
    // wq/wk splits live in d_out's s-region until scores overwrites it
    unsigned short* wqh = (unsigned short*)s;
    unsigned short* wql = wqh + DD;
    unsigned short* wkh = wql + DD;
    unsigned short* wkl = wkh + DD;
    // after scores: p reuses Qh+Ql, V reuses Kh
    unsigned short* p  = Qh;
    unsigned short* Vb = Kh;

    dim3 blk(256);

    split2_kernel<<<dim3(2048), blk, 0, stream>>>(x, xh, xl, BSD);
    split2_kernel<<<dim3(1024), blk, 0, stream>>>(wq, wqh, wql, DD);
    split2_kernel<<<dim3(1024), blk, 0, stream>>>(wk, wkh, wkl, DD);

    // Q = x @ wq^T, K = x @ wk^T  (3-term, split-bf16 outputs)
    mfma_gemm<3, true, 1, false><<<dim3(128, 8, 1), blk, 0, stream>>>(
        xh, xl, 0, D, wqh, wql, 0, D, nullptr, Qh, Ql, 0, D, D, nullptr, 0);
    mfma_gemm<3, true, 1, false><<<dim3(128, 8, 1), blk, 0, stream>>>(
        xh, xl, 0, D, wkh, wkl, 0, D, nullptr, Kh, Kl, 0, D, D, nullptr, 0);

    // scores = Q @ K^T + NEG_INF*mask  (3-term, f32 out)
    mfma_gemm<3, true, 0, false><<<dim3(16, 16, 8), blk, 0, stream>>>(
        Qh, Ql, SD, D, Kh, Kl, SD, D, s, nullptr, nullptr, SS, S, D, mask, S);

    // softmax in place + bf16 p for PV
    softmax_kernel<<<dim3(16384), blk, 0, stream>>>(s, p);

    // V = x @ wv^T  (1-term, wv converted in-kernel, bf16 out)
    mfma_gemm<1, true, 2, true><<<dim3(128, 8, 1), blk, 0, stream>>>(
        xh, nullptr, 0, D, wv, nullptr, 0, D, nullptr, Vb, nullptr, 0, D, D, nullptr, 0);

    // out = p @ V  (1-term, NN, f32 out)
    mfma_gemm<1, false, 0, false><<<dim3(16, 8, 8), blk, 0, stream>>>(
        p, nullptr, SS, S, Vb, nullptr, SD, D, out, nullptr, nullptr, SD, D, S, nullptr, 0);
}

// Round 3
// 695.047 us; speedup vs baseline: 4.6661x; 1.2966x over previous
//
#include <hip/hip_runtime.h>

#define NEG_INF_F (-1.0e9f)

typedef short bf16x8 __attribute__((ext_vector_type(8)));
typedef float f32x4 __attribute__((ext_vector_type(4)));

__device__ inline unsigned short bf_rne(float f) {
    unsigned u = __builtin_bit_cast(unsigned, f);
    u = (u + 0x7fffu + ((u >> 16) & 1u)) >> 16;
    return (unsigned short)u;
}
__device__ inline float bf_to_f32(unsigned short h) {
    unsigned u = ((unsigned)h) << 16;
    return __builtin_bit_cast(float, u);
}

// async global->LDS, 16B per lane; LDS dest = wave-uniform base + lane*16
__device__ inline void gload16(const unsigned short* g, unsigned short* l) {
    __builtin_amdgcn_global_load_lds(
        (const __attribute__((address_space(1))) unsigned int*)g,
        (__attribute__((address_space(3))) unsigned int*)l, 16, 0, 0);
}

// Stage one 128x32-bf16 tile (8KB). Wave w covers rows [w*32, w*32+32).
// LDS is linear in physical chunks; the global source is inverse-swizzled so a
// swizzled ds_read sees logical layout. Swizzle: phys_slot = slot ^ ((row>>1)&3).
__device__ inline void stage_tile(const unsigned short* __restrict__ g, int ldg,
                                  unsigned short* lds, int w, int lane) {
#pragma unroll
    for (int j = 0; j < 2; ++j) {
        const int r = w * 32 + j * 16 + (lane >> 2);
        const int slog = (lane & 3) ^ ((r >> 1) & 3);
        gload16(g + (long long)r * ldg + slog * 8, lds + (w * 32 + j * 16) * 32);
    }
}

// Swizzled fragment read: row's k-slot lg (8 bf16 = 16B)
__device__ inline bf16x8 frag(const unsigned short* t, int row, int lg) {
    const int ch = row * 4 + (lg ^ ((row >> 1) & 3));
    return *reinterpret_cast<const bf16x8*>(&t[ch * 8]);
}

// C = A * B^T, bf16 MFMA, 128x128 tile, BK=32, 4 waves (2x2), 4x4 frags.
// TERMS: 3 = hi/lo split (Ah*Bh + Al*Bh + Ah*Bl), 1 = hi only.
// OMODE: 0 = f32 C (+ optional NEG_INF*mask[col]); 1 = split bf16 (Ch,Cl);
//        3 = bf16 transposed V^T store: Ch[b2][col][s], b2=row>>11, s=row&2047.
template <int TERMS, int OMODE>
__global__ __launch_bounds__(256) void mfma_gemm(
    const unsigned short* __restrict__ Ah_g, const unsigned short* __restrict__ Al_g,
    long long strideA, int lda,
    const unsigned short* __restrict__ Bh_g, const unsigned short* __restrict__ Bl_g,
    long long strideB, int ldb,
    float* __restrict__ Cf, unsigned short* __restrict__ Ch, unsigned short* __restrict__ Cl,
    long long strideC, int ldc, int K,
    const int* __restrict__ mask, long long strideMask)
{
    const int b = blockIdx.z;
    const int tid = threadIdx.x;
    const int rowBase = blockIdx.x * 128;
    const int colBase = blockIdx.y * 128;

    __shared__ unsigned short smem[(TERMS == 3) ? 16384 : 8192];
    unsigned short* AsH = smem;
    unsigned short* BsH = smem + 4096;
    unsigned short* AsL = (TERMS == 3) ? smem + 8192 : smem;
    unsigned short* BsL = (TERMS == 3) ? smem + 12288 : smem;

    const int w = tid >> 6;
    const int lane = tid & 63;
    const int wr = w >> 1, wc = w & 1;
    const int lr = lane & 15, lg = lane >> 4;

    const unsigned short* Ah0 = Ah_g + (long long)b * strideA + (long long)rowBase * lda;
    const unsigned short* Bh0 = Bh_g + (long long)b * strideB + (long long)colBase * ldb;
    const unsigned short* Al0 = (TERMS == 3) ? Al_g + (long long)b * strideA + (long long)rowBase * lda : nullptr;
    const unsigned short* Bl0 = (TERMS == 3) ? Bl_g + (long long)b * strideB + (long long)colBase * ldb : nullptr;

    f32x4 acc[4][4] = {};

    for (int k0 = 0; k0 < K; k0 += 32) {
        __syncthreads();
        stage_tile(Ah0 + k0, lda, AsH, w, lane);
        stage_tile(Bh0 + k0, ldb, BsH, w, lane);
        if constexpr (TERMS == 3) {
            stage_tile(Al0 + k0, lda, AsL, w, lane);
            stage_tile(Bl0 + k0, ldb, BsL, w, lane);
        }
        __syncthreads();

        bf16x8 ah[4], bh[4], al[4], bl[4];
#pragma unroll
        for (int i = 0; i < 4; ++i) {
            ah[i] = frag(AsH, wr * 64 + i * 16 + lr, lg);
            bh[i] = frag(BsH, wc * 64 + i * 16 + lr, lg);
            if constexpr (TERMS == 3) {
                al[i] = frag(AsL, wr * 64 + i * 16 + lr, lg);
                bl[i] = frag(BsL, wc * 64 + i * 16 + lr, lg);
            }
        }
#pragma unroll
        for (int i = 0; i < 4; ++i)
#pragma unroll
            for (int j = 0; j < 4; ++j) {
                acc[i][j] = __builtin_amdgcn_mfma_f32_16x16x32_bf16(ah[i], bh[j], acc[i][j], 0, 0, 0);
                if constexpr (TERMS == 3) {
                    acc[i][j] = __builtin_amdgcn_mfma_f32_16x16x32_bf16(al[i], bh[j], acc[i][j], 0, 0, 0);
                    acc[i][j] = __builtin_amdgcn_mfma_f32_16x16x32_bf16(ah[i], bl[j], acc[i][j], 0, 0, 0);
                }
            }
    }

    // ---- epilogue: LDS-bounce to get vectorized, coalesced stores ----
    __syncthreads();
    float* stg = reinterpret_cast<float*>(smem) + w * 1024;  // 4KB per wave
    const int colg0 = colBase + wc * 64;
#pragma unroll
    for (int i = 0; i < 4; ++i) {
        const int rowg0 = rowBase + wr * 64 + i * 16;
#pragma unroll
        for (int j = 0; j < 4; ++j)
#pragma unroll
            for (int r2 = 0; r2 < 4; ++r2)
                stg[(lg * 4 + r2) * 64 + j * 16 + lr] = acc[i][j][r2];
        __syncthreads();

        if constexpr (OMODE == 0) {
#pragma unroll
            for (int t = 0; t < 4; ++t) {
                const int idx = t * 256 + lane * 4;
                const int r = idx >> 6, c = idx & 63;
                float4 v = *reinterpret_cast<const float4*>(&stg[idx]);
                const int colg = colg0 + c;
                if (mask != nullptr) {
                    const int4 mv = *reinterpret_cast<const int4*>(
                        &mask[(long long)b * strideMask + colg]);
                    v.x += NEG_INF_F * (float)mv.x;
                    v.y += NEG_INF_F * (float)mv.y;
                    v.z += NEG_INF_F * (float)mv.z;
                    v.w += NEG_INF_F * (float)mv.w;
                }
                *reinterpret_cast<float4*>(
                    &Cf[(long long)b * strideC + (long long)(rowg0 + r) * ldc + colg]) = v;
            }
        } else if constexpr (OMODE == 1) {
#pragma unroll
            for (int t = 0; t < 4; ++t) {
                const int idx = t * 256 + lane * 4;
                const int r = idx >> 6, c = idx & 63;
                const float4 v = *reinterpret_cast<const float4*>(&stg[idx]);
                ushort4 h, l;
                h.x = bf_rne(v.x); l.x = bf_rne(v.x - bf_to_f32(h.x));
                h.y = bf_rne(v.y); l.y = bf_rne(v.y - bf_to_f32(h.y));
                h.z = bf_rne(v.z); l.z = bf_rne(v.z - bf_to_f32(h.z));
                h.w = bf_rne(v.w); l.w = bf_rne(v.w - bf_to_f32(h.w));
                const long long cidx = (long long)(rowg0 + r) * ldc + colg0 + c;
                *reinterpret_cast<ushort4*>(&Ch[cidx]) = h;
                *reinterpret_cast<ushort4*>(&Cl[cidx]) = l;
            }
        } else {  // OMODE 3: V^T store
            const int b2 = rowg0 >> 11;
            const int s0 = rowg0 & 2047;
            const int colg = colg0 + lane;
            alignas(16) unsigned short u[16];
#pragma unroll
            for (int r = 0; r < 16; ++r) u[r] = bf_rne(stg[r * 64 + lane]);
            unsigned short* vp = Ch + (long long)b2 * (1024LL * 2048)
                               + (long long)colg * 2048 + s0;
            *reinterpret_cast<uint4*>(vp)     = *reinterpret_cast<const uint4*>(&u[0]);
            *reinterpret_cast<uint4*>(vp + 8) = *reinterpret_cast<const uint4*>(&u[8]);
        }
        __syncthreads();
    }
}

// f32 -> (hi, lo) bf16 split
__global__ __launch_bounds__(256) void split2_kernel(
    const float* __restrict__ in, unsigned short* __restrict__ hi,
    unsigned short* __restrict__ lo, long long n)
{
    for (long long i = ((long long)blockIdx.x * 256 + threadIdx.x) * 4; i < n;
         i += (long long)gridDim.x * 256 * 4) {
        float4 v = *reinterpret_cast<const float4*>(&in[i]);
        ushort4 h, l;
        h.x = bf_rne(v.x); l.x = bf_rne(v.x - bf_to_f32(h.x));
        h.y = bf_rne(v.y); l.y = bf_rne(v.y - bf_to_f32(h.y));
        h.z = bf_rne(v.z); l.z = bf_rne(v.z - bf_to_f32(h.z));
        h.w = bf_rne(v.w); l.w = bf_rne(v.w - bf_to_f32(h.w));
        *reinterpret_cast<ushort4*>(&hi[i]) = h;
        *reinterpret_cast<ushort4*>(&lo[i]) = l;
    }
}

// f32 -> bf16
__global__ __launch_bounds__(256) void cvt_kernel(
    const float* __restrict__ in, unsigned short* __restrict__ out, long long n)
{
    for (long long i = ((long long)blockIdx.x * 256 + threadIdx.x) * 4; i < n;
         i += (long long)gridDim.x * 256 * 4) {
        float4 v = *reinterpret_cast<const float4*>(&in[i]);
        ushort4 h;
        h.x = bf_rne(v.x); h.y = bf_rne(v.y); h.z = bf_rne(v.z); h.w = bf_rne(v.w);
        *reinterpret_cast<ushort4*>(&out[i]) = h;
    }
}

// In-place f32 row softmax (rows=16384, cols=2048) + bf16 copy for PV.
__global__ __launch_bounds__(256) void softmax_kernel(
    float* __restrict__ s, unsigned short* __restrict__ p)
{
    const long long row = blockIdx.x;
    float* sp = s + row * 2048;
    const int tid = threadIdx.x;

    float v[8];
    *reinterpret_cast<float4*>(&v[0]) = *reinterpret_cast<const float4*>(&sp[tid * 8]);
    *reinterpret_cast<float4*>(&v[4]) = *reinterpret_cast<const float4*>(&sp[tid * 8 + 4]);

    float m = v[0];
#pragma unroll
    for (int i = 1; i < 8; ++i) m = fmaxf(m, v[i]);
#pragma unroll
    for (int off = 1; off < 64; off <<= 1) m = fmaxf(m, __shfl_xor(m, off));

    __shared__ float redm[4];
    __shared__ float reds[4];
    if ((tid & 63) == 0) redm[tid >> 6] = m;
    __syncthreads();
    m = fmaxf(fmaxf(redm[0], redm[1]), fmaxf(redm[2], redm[3]));

    float sum = 0.f;
#pragma unroll
    for (int i = 0; i < 8; ++i) {
        v[i] = __expf(v[i] - m);
        sum += v[i];
    }
#pragma unroll
    for (int off = 1; off < 64; off <<= 1) sum += __shfl_xor(sum, off);
    if ((tid & 63) == 0) reds[tid >> 6] = sum;
    __syncthreads();
    sum = reds[0] + reds[1] + reds[2] + reds[3];

    const float inv = 1.0f / sum;
#pragma unroll
    for (int i = 0; i < 8; ++i) v[i] *= inv;

    *reinterpret_cast<float4*>(&sp[tid * 8])     = *reinterpret_cast<const float4*>(&v[0]);
    *reinterpret_cast<float4*>(&sp[tid * 8 + 4]) = *reinterpret_cast<const float4*>(&v[4]);

    ushort4 o0, o1;
    o0.x = bf_rne(v[0]); o0.y = bf_rne(v[1]); o0.z = bf_rne(v[2]); o0.w = bf_rne(v[3]);
    o1.x = bf_rne(v[4]); o1.y = bf_rne(v[5]); o1.z = bf_rne(v[6]); o1.w = bf_rne(v[7]);
    *reinterpret_cast<ushort4*>(&p[row * 2048 + tid * 8])     = o0;
    *reinterpret_cast<ushort4*>(&p[row * 2048 + tid * 8 + 4]) = o1;
}

extern "C" void kernel_launch(void* const* d_in, const int* in_sizes, int n_in,
                              void* d_out, int out_size, void* d_ws, size_t ws_size,
                              hipStream_t stream)
{
    (void)in_sizes; (void)n_in; (void)out_size; (void)ws_size;

    const int S = 2048, D = 1024;
    const long long BS  = 8LL * S;
    const long long SD  = (long long)S * D;
    const long long SS  = (long long)S * S;
    const long long BSD = BS * D;
    const long long DD  = (long long)D * D;

    const float* x    = (const float*)d_in[0];
    const int*   mask = (const int*)d_in[1];
    const float* wq   = (const float*)d_in[2];
    const float* wk   = (const float*)d_in[3];
    const float* wv   = (const float*)d_in[4];

    float* out = (float*)d_out;           // [BS, D] f32 (final)
    float* s   = out + BSD;               // [B, S, S] f32 (final)

    // ws: Qh | Ql | Kh | Kl  (bf16, each BSD elems)
    unsigned short* Qh = (unsigned short*)d_ws;
    unsigned short* Ql = Qh + BSD;
    unsigned short* Kh = Ql + BSD;
    unsigned short* Kl = Kh + BSD;

    // x split lives in d_out's out-region until PV overwrites it
    unsigned short* xh = (unsigned short*)out;
    unsigned short* xl = xh + BSD;
    // wq/wk splits live in d_out's s-region until scores overwrites it
    unsigned short* wqh = (unsigned short*)s;
    unsigned short* wql = wqh + DD;
    unsigned short* wkh = wql + DD;
    unsigned short* wkl = wkh + DD;
    // after scores: p reuses Qh+Ql, V^T reuses Kh, wv-bf16 reuses Kl
    unsigned short* p   = Qh;
    unsigned short* Vt  = Kh;
    unsigned short* wvh = Kl;

    dim3 blk(256);

    split2_kernel<<<dim3(2048), blk, 0, stream>>>(x, xh, xl, BSD);
    split2_kernel<<<dim3(512), blk, 0, stream>>>(wq, wqh, wql, DD);
    split2_kernel<<<dim3(512), blk, 0, stream>>>(wk, wkh, wkl, DD);

    // Q = x @ wq^T, K = x @ wk^T  (3-term, split-bf16 outputs)
    mfma_gemm<3, 1><<<dim3(128, 8, 1), blk, 0, stream>>>(
        xh, xl, 0, D, wqh, wql, 0, D, nullptr, Qh, Ql, 0, D, D, nullptr, 0);
    mfma_gemm<3, 1><<<dim3(128, 8, 1), blk, 0, stream>>>(
        xh, xl, 0, D, wkh, wkl, 0, D, nullptr, Kh, Kl, 0, D, D, nullptr, 0);

    // scores = Q @ K^T + NEG_INF*mask  (3-term, f32 out)
    mfma_gemm<3, 0><<<dim3(16, 16, 8), blk, 0, stream>>>(
        Qh, Ql, SD, D, Kh, Kl, SD, D, s, nullptr, nullptr, SS, S, D, mask, S);

    // softmax in place + bf16 p for PV
    softmax_kernel<<<dim3(16384), blk, 0, stream>>>(s, p);

    // wv -> bf16, then V^T = (x @ wv^T)^T directly (1-term, transposed store)
    cvt_kernel<<<dim3(512), blk, 0, stream>>>(wv, wvh, DD);
    mfma_gemm<1, 3><<<dim3(128, 8, 1), blk, 0, stream>>>(
        xh, nullptr, 0, D, wvh, nullptr, 0, D, nullptr, Vt, nullptr, 0, 0, D, nullptr, 0);

    // out = p @ V = p @ (V^T)^T  (1-term, NT form, f32 out)
    mfma_gemm<1, 0><<<dim3(16, 8, 8), blk, 0, stream>>>(
        p, nullptr, SS, S, Vt, nullptr, SD, S, out, nullptr, nullptr, SD, D, S, nullptr, 0);
}

// Round 4
// 531.213 us; speedup vs baseline: 6.1051x; 1.3084x over previous
//
#include <hip/hip_runtime.h>

#define NEG_INF_F (-1.0e9f)

typedef short bf16x8 __attribute__((ext_vector_type(8)));
typedef float f32x4 __attribute__((ext_vector_type(4)));

__device__ inline unsigned short bf_rne(float f) {
    unsigned u = __builtin_bit_cast(unsigned, f);
    u = (u + 0x7fffu + ((u >> 16) & 1u)) >> 16;
    return (unsigned short)u;
}
__device__ inline float bf_to_f32(unsigned short h) {
    unsigned u = ((unsigned)h) << 16;
    return __builtin_bit_cast(float, u);
}

// async global->LDS, 16B per lane; LDS dest = wave-uniform base + lane*16
__device__ inline void gload16(const unsigned short* g, unsigned short* l) {
    __builtin_amdgcn_global_load_lds(
        (const __attribute__((address_space(1))) unsigned int*)g,
        (__attribute__((address_space(3))) unsigned int*)l, 16, 0, 0);
}

// ---------------- 256x256 8-wave double-buffered GEMM ----------------
// C = A * B^T. TERMS: 3 = split hi/lo (Ah*Bh+Al*Bh+Ah*Bl), BK=32;
//              1 = hi only, BK=64.
// OMODE: 0 = f32 C (+ optional NEG_INF*mask[col]); 1 = split bf16 (Ch,Cl).
// LDS: 2 buffers x 64KB. Loop: issue next K-tile stage at iter top (into the
// idle buffer), compute current, single __syncthreads() drains at iter end.

// TERMS=3 tile [256][32] bf16 (8192 ushorts), chunk swizzle ^((r>>1)&3)
__device__ inline bf16x8 frag32(const unsigned short* t, int r, int lg) {
    return *reinterpret_cast<const bf16x8*>(&t[r * 32 + (lg ^ ((r >> 1) & 3)) * 8]);
}
// TERMS=1 tile [256][64] bf16 (16384 ushorts), chunk swizzle ^(r&7)
__device__ inline bf16x8 frag64(const unsigned short* t, int r, int ch) {
    return *reinterpret_cast<const bf16x8*>(&t[r * 64 + (ch ^ (r & 7)) * 8]);
}

template <int TERMS>
__device__ inline void stage_ktile(
    const unsigned short* __restrict__ Ah0, const unsigned short* __restrict__ Al0, int lda,
    const unsigned short* __restrict__ Bh0, const unsigned short* __restrict__ Bl0, int ldb,
    int k0, unsigned short* buf, int w, int lane)
{
    if constexpr (TERMS == 3) {
#pragma unroll
        for (int c = 0; c < 2; ++c) {
            const int r = c * 128 + w * 16 + (lane >> 2);
            const int co = ((lane & 3) ^ ((r >> 1) & 3)) * 8;
            const int lb = (c * 128 + w * 16) * 32;
            gload16(Ah0 + (long long)r * lda + k0 + co, buf + lb);
            gload16(Al0 + (long long)r * lda + k0 + co, buf + 8192 + lb);
            gload16(Bh0 + (long long)r * ldb + k0 + co, buf + 16384 + lb);
            gload16(Bl0 + (long long)r * ldb + k0 + co, buf + 24576 + lb);
        }
    } else {
#pragma unroll
        for (int c = 0; c < 4; ++c) {
            const int r = c * 64 + w * 8 + (lane >> 3);
            const int co = ((lane & 7) ^ (r & 7)) * 8;
            const int lb = (c * 64 + w * 8) * 64;
            gload16(Ah0 + (long long)r * lda + k0 + co, buf + lb);
            gload16(Bh0 + (long long)r * ldb + k0 + co, buf + 16384 + lb);
        }
    }
}

template <int TERMS, int OMODE>
__global__ __launch_bounds__(512, 2) void mfma_gemm256(
    const unsigned short* __restrict__ Ah_g, const unsigned short* __restrict__ Al_g,
    long long strideA, int lda,
    const unsigned short* __restrict__ Bh_g, const unsigned short* __restrict__ Bl_g,
    long long strideB, int ldb,
    float* __restrict__ Cf, unsigned short* __restrict__ Ch, unsigned short* __restrict__ Cl,
    long long strideC, int ldc, int K,
    const int* __restrict__ mask, long long strideMask)
{
    constexpr int KT = (TERMS == 3) ? 32 : 64;
    const int b = blockIdx.z;
    const int tid = threadIdx.x;
    const int w = tid >> 6, lane = tid & 63;
    const int wr = w >> 2, wc = w & 3;
    const int lr = lane & 15, lg = lane >> 4;
    const int rowBase = blockIdx.x * 256;
    const int colBase = blockIdx.y * 256;

    __shared__ unsigned short smem[65536];  // 128 KB: 2 x 64KB buffers

    const unsigned short* Ah0 = Ah_g + (long long)b * strideA + (long long)rowBase * lda;
    const unsigned short* Bh0 = Bh_g + (long long)b * strideB + (long long)colBase * ldb;
    const unsigned short* Al0 = (TERMS == 3)
        ? Al_g + (long long)b * strideA + (long long)rowBase * lda : nullptr;
    const unsigned short* Bl0 = (TERMS == 3)
        ? Bl_g + (long long)b * strideB + (long long)colBase * ldb : nullptr;

    f32x4 acc[8][4] = {};
    const int NT = K / KT;

    stage_ktile<TERMS>(Ah0, Al0, lda, Bh0, Bl0, ldb, 0, smem, w, lane);
    __syncthreads();

    for (int kt = 0; kt < NT; ++kt) {
        unsigned short* cbuf = smem + (kt & 1) * 32768;
        if (kt + 1 < NT)
            stage_ktile<TERMS>(Ah0, Al0, lda, Bh0, Bl0, ldb, (kt + 1) * KT,
                               smem + ((kt + 1) & 1) * 32768, w, lane);

        if constexpr (TERMS == 3) {
            const unsigned short* tAh = cbuf;
            const unsigned short* tAl = cbuf + 8192;
            const unsigned short* tBh = cbuf + 16384;
            const unsigned short* tBl = cbuf + 24576;
            bf16x8 bh[4], bl[4];
#pragma unroll
            for (int j = 0; j < 4; ++j) {
                const int r = wc * 64 + j * 16 + lr;
                bh[j] = frag32(tBh, r, lg);
                bl[j] = frag32(tBl, r, lg);
            }
#pragma unroll
            for (int ih = 0; ih < 2; ++ih) {
                bf16x8 ah[4], al[4];
#pragma unroll
                for (int f = 0; f < 4; ++f) {
                    const int r = wr * 128 + ih * 64 + f * 16 + lr;
                    ah[f] = frag32(tAh, r, lg);
                    al[f] = frag32(tAl, r, lg);
                }
#pragma unroll
                for (int f = 0; f < 4; ++f)
#pragma unroll
                    for (int j = 0; j < 4; ++j) {
                        f32x4 a = acc[ih * 4 + f][j];
                        a = __builtin_amdgcn_mfma_f32_16x16x32_bf16(ah[f], bh[j], a, 0, 0, 0);
                        a = __builtin_amdgcn_mfma_f32_16x16x32_bf16(al[f], bh[j], a, 0, 0, 0);
                        a = __builtin_amdgcn_mfma_f32_16x16x32_bf16(ah[f], bl[j], a, 0, 0, 0);
                        acc[ih * 4 + f][j] = a;
                    }
            }
        } else {
            const unsigned short* tA = cbuf;
            const unsigned short* tB = cbuf + 16384;
            bf16x8 bh[8];
#pragma unroll
            for (int j = 0; j < 4; ++j)
#pragma unroll
                for (int ks = 0; ks < 2; ++ks)
                    bh[j * 2 + ks] = frag64(tB, wc * 64 + j * 16 + lr, ks * 4 + lg);
#pragma unroll
            for (int ih = 0; ih < 2; ++ih) {
                bf16x8 ah[8];
#pragma unroll
                for (int f = 0; f < 4; ++f)
#pragma unroll
                    for (int ks = 0; ks < 2; ++ks)
                        ah[f * 2 + ks] = frag64(tA, wr * 128 + ih * 64 + f * 16 + lr, ks * 4 + lg);
#pragma unroll
                for (int f = 0; f < 4; ++f)
#pragma unroll
                    for (int j = 0; j < 4; ++j) {
                        f32x4 a = acc[ih * 4 + f][j];
                        a = __builtin_amdgcn_mfma_f32_16x16x32_bf16(ah[f * 2 + 0], bh[j * 2 + 0], a, 0, 0, 0);
                        a = __builtin_amdgcn_mfma_f32_16x16x32_bf16(ah[f * 2 + 1], bh[j * 2 + 1], a, 0, 0, 0);
                        acc[ih * 4 + f][j] = a;
                    }
            }
        }
        __syncthreads();
    }

    // ---- epilogue: per-wave LDS bounce (8KB region), 4 rounds of 32x64 ----
    float* stg = reinterpret_cast<float*>(smem) + w * 2048;
    const int colg0 = colBase + wc * 64;
#pragma unroll
    for (int rnd = 0; rnd < 4; ++rnd) {
        const int rowg0 = rowBase + wr * 128 + rnd * 32;
#pragma unroll
        for (int ii = 0; ii < 2; ++ii)
#pragma unroll
            for (int j = 0; j < 4; ++j)
#pragma unroll
                for (int r2 = 0; r2 < 4; ++r2)
                    stg[(ii * 16 + lg * 4 + r2) * 64 + j * 16 + lr] = acc[rnd * 2 + ii][j][r2];
        __syncthreads();

        if constexpr (OMODE == 0) {
#pragma unroll
            for (int t = 0; t < 8; ++t) {
                const int idx = t * 256 + lane * 4;
                const int r = idx >> 6, c = idx & 63;
                float4 v = *reinterpret_cast<const float4*>(&stg[idx]);
                const int colg = colg0 + c;
                if (mask != nullptr) {
                    const int4 mv = *reinterpret_cast<const int4*>(
                        &mask[(long long)b * strideMask + colg]);
                    v.x += NEG_INF_F * (float)mv.x;
                    v.y += NEG_INF_F * (float)mv.y;
                    v.z += NEG_INF_F * (float)mv.z;
                    v.w += NEG_INF_F * (float)mv.w;
                }
                *reinterpret_cast<float4*>(
                    &Cf[(long long)b * strideC + (long long)(rowg0 + r) * ldc + colg]) = v;
            }
        } else {
#pragma unroll
            for (int t = 0; t < 8; ++t) {
                const int idx = t * 256 + lane * 4;
                const int r = idx >> 6, c = idx & 63;
                const float4 v = *reinterpret_cast<const float4*>(&stg[idx]);
                ushort4 h, l;
                h.x = bf_rne(v.x); l.x = bf_rne(v.x - bf_to_f32(h.x));
                h.y = bf_rne(v.y); l.y = bf_rne(v.y - bf_to_f32(h.y));
                h.z = bf_rne(v.z); l.z = bf_rne(v.z - bf_to_f32(h.z));
                h.w = bf_rne(v.w); l.w = bf_rne(v.w - bf_to_f32(h.w));
                const long long cidx = (long long)(rowg0 + r) * ldc + colg0 + c;
                *reinterpret_cast<ushort4*>(&Ch[cidx]) = h;
                *reinterpret_cast<ushort4*>(&Cl[cidx]) = l;
            }
        }
        __syncthreads();
    }
}

// ---------------- old 128x128 4-wave kernel (V^T projection only) ----------------
__device__ inline void stage_tile128(const unsigned short* __restrict__ g, int ldg,
                                     unsigned short* lds, int w, int lane) {
#pragma unroll
    for (int j = 0; j < 2; ++j) {
        const int r = w * 32 + j * 16 + (lane >> 2);
        const int slog = (lane & 3) ^ ((r >> 1) & 3);
        gload16(g + (long long)r * ldg + slog * 8, lds + (w * 32 + j * 16) * 32);
    }
}

// 1-term, B^T input, OMODE 3: bf16 transposed V^T store Ch[b2][col][s]
__global__ __launch_bounds__(256) void mfma_gemm128_vt(
    const unsigned short* __restrict__ Ah_g, int lda,
    const unsigned short* __restrict__ Bh_g, int ldb,
    unsigned short* __restrict__ Ch, int K)
{
    const int tid = threadIdx.x;
    const int rowBase = blockIdx.x * 128;
    const int colBase = blockIdx.y * 128;

    __shared__ unsigned short smem[8192];
    unsigned short* AsH = smem;
    unsigned short* BsH = smem + 4096;

    const int w = tid >> 6;
    const int lane = tid & 63;
    const int wr = w >> 1, wc = w & 1;
    const int lr = lane & 15, lg = lane >> 4;

    const unsigned short* Ah0 = Ah_g + (long long)rowBase * lda;
    const unsigned short* Bh0 = Bh_g + (long long)colBase * ldb;

    f32x4 acc[4][4] = {};

    for (int k0 = 0; k0 < K; k0 += 32) {
        __syncthreads();
        stage_tile128(Ah0 + k0, lda, AsH, w, lane);
        stage_tile128(Bh0 + k0, ldb, BsH, w, lane);
        __syncthreads();

        bf16x8 ah[4], bh[4];
#pragma unroll
        for (int i = 0; i < 4; ++i) {
            ah[i] = frag32(AsH, wr * 64 + i * 16 + lr, lg);
            bh[i] = frag32(BsH, wc * 64 + i * 16 + lr, lg);
        }
#pragma unroll
        for (int i = 0; i < 4; ++i)
#pragma unroll
            for (int j = 0; j < 4; ++j)
                acc[i][j] = __builtin_amdgcn_mfma_f32_16x16x32_bf16(ah[i], bh[j], acc[i][j], 0, 0, 0);
    }

    __syncthreads();
    float* stg = reinterpret_cast<float*>(smem) + w * 1024;
    const int colg0 = colBase + wc * 64;
#pragma unroll
    for (int i = 0; i < 4; ++i) {
        const int rowg0 = rowBase + wr * 64 + i * 16;
#pragma unroll
        for (int j = 0; j < 4; ++j)
#pragma unroll
            for (int r2 = 0; r2 < 4; ++r2)
                stg[(lg * 4 + r2) * 64 + j * 16 + lr] = acc[i][j][r2];
        __syncthreads();

        const int b2 = rowg0 >> 11;
        const int s0 = rowg0 & 2047;
        const int colg = colg0 + lane;
        alignas(16) unsigned short u[16];
#pragma unroll
        for (int r = 0; r < 16; ++r) u[r] = bf_rne(stg[r * 64 + lane]);
        unsigned short* vp = Ch + (long long)b2 * (1024LL * 2048)
                           + (long long)colg * 2048 + s0;
        *reinterpret_cast<uint4*>(vp)     = *reinterpret_cast<const uint4*>(&u[0]);
        *reinterpret_cast<uint4*>(vp + 8) = *reinterpret_cast<const uint4*>(&u[8]);
        __syncthreads();
    }
}

// ---------------- helpers ----------------
__global__ __launch_bounds__(256) void split2_kernel(
    const float* __restrict__ in, unsigned short* __restrict__ hi,
    unsigned short* __restrict__ lo, long long n)
{
    for (long long i = ((long long)blockIdx.x * 256 + threadIdx.x) * 4; i < n;
         i += (long long)gridDim.x * 256 * 4) {
        float4 v = *reinterpret_cast<const float4*>(&in[i]);
        ushort4 h, l;
        h.x = bf_rne(v.x); l.x = bf_rne(v.x - bf_to_f32(h.x));
        h.y = bf_rne(v.y); l.y = bf_rne(v.y - bf_to_f32(h.y));
        h.z = bf_rne(v.z); l.z = bf_rne(v.z - bf_to_f32(h.z));
        h.w = bf_rne(v.w); l.w = bf_rne(v.w - bf_to_f32(h.w));
        *reinterpret_cast<ushort4*>(&hi[i]) = h;
        *reinterpret_cast<ushort4*>(&lo[i]) = l;
    }
}

__global__ __launch_bounds__(256) void cvt_kernel(
    const float* __restrict__ in, unsigned short* __restrict__ out, long long n)
{
    for (long long i = ((long long)blockIdx.x * 256 + threadIdx.x) * 4; i < n;
         i += (long long)gridDim.x * 256 * 4) {
        float4 v = *reinterpret_cast<const float4*>(&in[i]);
        ushort4 h;
        h.x = bf_rne(v.x); h.y = bf_rne(v.y); h.z = bf_rne(v.z); h.w = bf_rne(v.w);
        *reinterpret_cast<ushort4*>(&out[i]) = h;
    }
}

__global__ __launch_bounds__(256) void softmax_kernel(
    float* __restrict__ s, unsigned short* __restrict__ p)
{
    const long long row = blockIdx.x;
    float* sp = s + row * 2048;
    const int tid = threadIdx.x;

    float v[8];
    *reinterpret_cast<float4*>(&v[0]) = *reinterpret_cast<const float4*>(&sp[tid * 8]);
    *reinterpret_cast<float4*>(&v[4]) = *reinterpret_cast<const float4*>(&sp[tid * 8 + 4]);

    float m = v[0];
#pragma unroll
    for (int i = 1; i < 8; ++i) m = fmaxf(m, v[i]);
#pragma unroll
    for (int off = 1; off < 64; off <<= 1) m = fmaxf(m, __shfl_xor(m, off));

    __shared__ float redm[4];
    __shared__ float reds[4];
    if ((tid & 63) == 0) redm[tid >> 6] = m;
    __syncthreads();
    m = fmaxf(fmaxf(redm[0], redm[1]), fmaxf(redm[2], redm[3]));

    float sum = 0.f;
#pragma unroll
    for (int i = 0; i < 8; ++i) {
        v[i] = __expf(v[i] - m);
        sum += v[i];
    }
#pragma unroll
    for (int off = 1; off < 64; off <<= 1) sum += __shfl_xor(sum, off);
    if ((tid & 63) == 0) reds[tid >> 6] = sum;
    __syncthreads();
    sum = reds[0] + reds[1] + reds[2] + reds[3];

    const float inv = 1.0f / sum;
#pragma unroll
    for (int i = 0; i < 8; ++i) v[i] *= inv;

    *reinterpret_cast<float4*>(&sp[tid * 8])     = *reinterpret_cast<const float4*>(&v[0]);
    *reinterpret_cast<float4*>(&sp[tid * 8 + 4]) = *reinterpret_cast<const float4*>(&v[4]);

    ushort4 o0, o1;
    o0.x = bf_rne(v[0]); o0.y = bf_rne(v[1]); o0.z = bf_rne(v[2]); o0.w = bf_rne(v[3]);
    o1.x = bf_rne(v[4]); o1.y = bf_rne(v[5]); o1.z = bf_rne(v[6]); o1.w = bf_rne(v[7]);
    *reinterpret_cast<ushort4*>(&p[row * 2048 + tid * 8])     = o0;
    *reinterpret_cast<ushort4*>(&p[row * 2048 + tid * 8 + 4]) = o1;
}

extern "C" void kernel_launch(void* const* d_in, const int* in_sizes, int n_in,
                              void* d_out, int out_size, void* d_ws, size_t ws_size,
                              hipStream_t stream)
{
    (void)in_sizes; (void)n_in; (void)out_size; (void)ws_size;

    const int S = 2048, D = 1024;
    const long long BS  = 8LL * S;
    const long long SD  = (long long)S * D;
    const long long SS  = (long long)S * S;
    const long long BSD = BS * D;
    const long long DD  = (long long)D * D;

    const float* x    = (const float*)d_in[0];
    const int*   mask = (const int*)d_in[1];
    const float* wq   = (const float*)d_in[2];
    const float* wk   = (const float*)d_in[3];
    const float* wv   = (const float*)d_in[4];

    float* out = (float*)d_out;           // [BS, D] f32 (final)
    float* s   = out + BSD;               // [B, S, S] f32 (final)

    // ws: Qh | Ql | Kh | Kl  (bf16, each BSD elems)
    unsigned short* Qh = (unsigned short*)d_ws;
    unsigned short* Ql = Qh + BSD;
    unsigned short* Kh = Ql + BSD;
    unsigned short* Kl = Kh + BSD;

    // x split lives in d_out's out-region until PV overwrites it
    unsigned short* xh = (unsigned short*)out;
    unsigned short* xl = xh + BSD;
    // wq/wk splits live in d_out's s-region until scores overwrites it
    unsigned short* wqh = (unsigned short*)s;
    unsigned short* wql = wqh + DD;
    unsigned short* wkh = wql + DD;
    unsigned short* wkl = wkh + DD;
    // after scores: p reuses Qh+Ql, V^T reuses Kh, wv-bf16 reuses Kl
    unsigned short* p   = Qh;
    unsigned short* Vt  = Kh;
    unsigned short* wvh = Kl;

    dim3 blk256(256), blk512(512);

    split2_kernel<<<dim3(2048), blk256, 0, stream>>>(x, xh, xl, BSD);
    split2_kernel<<<dim3(512), blk256, 0, stream>>>(wq, wqh, wql, DD);
    split2_kernel<<<dim3(512), blk256, 0, stream>>>(wk, wkh, wkl, DD);

    // Q = x @ wq^T, K = x @ wk^T  (3-term, split-bf16 outputs)
    mfma_gemm256<3, 1><<<dim3(64, 4, 1), blk512, 0, stream>>>(
        xh, xl, 0, D, wqh, wql, 0, D, nullptr, Qh, Ql, 0, D, D, nullptr, 0);
    mfma_gemm256<3, 1><<<dim3(64, 4, 1), blk512, 0, stream>>>(
        xh, xl, 0, D, wkh, wkl, 0, D, nullptr, Kh, Kl, 0, D, D, nullptr, 0);

    // scores = Q @ K^T + NEG_INF*mask  (3-term, f32 out)
    mfma_gemm256<3, 0><<<dim3(8, 8, 8), blk512, 0, stream>>>(
        Qh, Ql, SD, D, Kh, Kl, SD, D, s, nullptr, nullptr, SS, S, D, mask, S);

    // softmax in place + bf16 p for PV
    softmax_kernel<<<dim3(16384), blk256, 0, stream>>>(s, p);

    // wv -> bf16, then V^T = (x @ wv^T)^T directly (1-term, transposed store)
    cvt_kernel<<<dim3(512), blk256, 0, stream>>>(wv, wvh, DD);
    mfma_gemm128_vt<<<dim3(128, 8, 1), blk256, 0, stream>>>(
        xh, D, wvh, D, Vt, D);

    // out = p @ V = p @ (V^T)^T  (1-term BK=64, NT form, f32 out)
    mfma_gemm256<1, 0><<<dim3(8, 4, 8), blk512, 0, stream>>>(
        p, nullptr, SS, S, Vt, nullptr, SD, S, out, nullptr, nullptr, SD, D, S, nullptr, 0);
}